// Round 1
// baseline (1090.575 us; speedup 1.0000x reference)
//
#include <hip/hip_runtime.h>

#define B_ 8
#define NQ_ 2048
#define NK_ 2048
#define D_ 256

// ---------------------------------------------------------------------------
// qr[b,i,d] = sum_n cos(2*pi*i*n/2048) * query[b,n,d]   (Re of FFT along seq)
// Only rows i in [0, 1087] computed here (17 x-blocks); rest mirrored.
// ---------------------------------------------------------------------------
__global__ __launch_bounds__(256) void dft_kernel(const float* __restrict__ query,
                                                  float* __restrict__ qr) {
  __shared__ float cost[2048];
  __shared__ float Cs[64][17];   // [i][n]
  __shared__ float Qs[16][65];   // [n][d]
  const int t  = threadIdx.x;
  const int b  = blockIdx.z;
  const int i0 = blockIdx.x * 64;
  const int d0 = blockIdx.y * 64;

  for (int idx = t; idx < 2048; idx += 256)
    cost[idx] = __cosf((float)idx * (6.28318530717958647692f / 2048.0f));
  __syncthreads();

  const int tx = t & 15, ty = t >> 4;
  float acc[4][4];
#pragma unroll
  for (int r = 0; r < 4; ++r)
#pragma unroll
    for (int c = 0; c < 4; ++c) acc[r][c] = 0.f;

  for (int n0 = 0; n0 < NQ_; n0 += 16) {
    {
      const int dd = t & 63, ng = t >> 6;
#pragma unroll
      for (int p = 0; p < 4; ++p) {
        const int nn = ng * 4 + p;
        Qs[nn][dd] = query[((size_t)b * NQ_ + n0 + nn) * D_ + d0 + dd];
      }
    }
    {
      const int nn = t & 15, ig = t >> 4;
#pragma unroll
      for (int p = 0; p < 4; ++p) {
        const int ii = ig + 16 * p;
        Cs[ii][nn] = cost[((i0 + ii) * (n0 + nn)) & 2047];
      }
    }
    __syncthreads();
#pragma unroll
    for (int kk = 0; kk < 16; ++kk) {
      float a[4], bb[4];
#pragma unroll
      for (int r = 0; r < 4; ++r) a[r] = Cs[ty + 16 * r][kk];
#pragma unroll
      for (int c = 0; c < 4; ++c) bb[c] = Qs[kk][tx + 16 * c];
#pragma unroll
      for (int r = 0; r < 4; ++r)
#pragma unroll
        for (int c = 0; c < 4; ++c) acc[r][c] += a[r] * bb[c];
    }
    __syncthreads();
  }
#pragma unroll
  for (int r = 0; r < 4; ++r) {
    const int i = i0 + ty + 16 * r;
#pragma unroll
    for (int c = 0; c < 4; ++c) {
      const int d = d0 + tx + 16 * c;
      qr[((size_t)b * NQ_ + i) * D_ + d] = acc[r][c];
    }
  }
}

// qr[b,i,:] = qr[b,2048-i,:] for i in [1088, 2047]
__global__ __launch_bounds__(256) void mirror_kernel(float* __restrict__ qr) {
  const int i = 1088 + blockIdx.x;   // 1088..2047
  const int b = blockIdx.y;
  const int src = 2048 - i;          // 960..1
  qr[((size_t)b * NQ_ + i) * D_ + threadIdx.x] =
      qr[((size_t)b * NQ_ + src) * D_ + threadIdx.x];
}

// ---------------------------------------------------------------------------
// y[m,o] = sum_i x[m,i] * W[o,i] + bias[o]      (torch Linear: x @ W.T + b)
// ---------------------------------------------------------------------------
__global__ __launch_bounds__(256) void proj_kernel(const float* __restrict__ x,
                                                   const float* __restrict__ W,
                                                   const float* __restrict__ bias,
                                                   float* __restrict__ y) {
  __shared__ float Xs[64][17];
  __shared__ float Ws[64][17];
  const int t  = threadIdx.x;
  const int m0 = blockIdx.x * 64;
  const int o0 = blockIdx.y * 64;
  const int tx = t & 15, ty = t >> 4;
  float acc[4][4];
#pragma unroll
  for (int r = 0; r < 4; ++r)
#pragma unroll
    for (int c = 0; c < 4; ++c) acc[r][c] = 0.f;

  for (int k0 = 0; k0 < D_; k0 += 16) {
    const int ii = t & 15, rg = t >> 4;
#pragma unroll
    for (int p = 0; p < 4; ++p) {
      Xs[rg + 16 * p][ii] = x[(size_t)(m0 + rg + 16 * p) * D_ + k0 + ii];
      Ws[rg + 16 * p][ii] = W[(size_t)(o0 + rg + 16 * p) * D_ + k0 + ii];
    }
    __syncthreads();
#pragma unroll
    for (int kk = 0; kk < 16; ++kk) {
      float a[4], bb[4];
#pragma unroll
      for (int r = 0; r < 4; ++r) a[r] = Xs[ty + 16 * r][kk];
#pragma unroll
      for (int c = 0; c < 4; ++c) bb[c] = Ws[tx + 16 * c][kk];
#pragma unroll
      for (int r = 0; r < 4; ++r)
#pragma unroll
        for (int c = 0; c < 4; ++c) acc[r][c] += a[r] * bb[c];
    }
    __syncthreads();
  }
#pragma unroll
  for (int r = 0; r < 4; ++r) {
    const int m = m0 + ty + 16 * r;
#pragma unroll
    for (int c = 0; c < 4; ++c) {
      const int o = o0 + tx + 16 * c;
      y[(size_t)m * D_ + o] = acc[r][c] + bias[o];
    }
  }
}

// ---------------------------------------------------------------------------
// S[b,i,j] = scale * sum_d q[b,i,d] * k[b,j,d]
// ---------------------------------------------------------------------------
__global__ __launch_bounds__(256) void scores_kernel(const float* __restrict__ q,
                                                     const float* __restrict__ k,
                                                     float* __restrict__ S) {
  __shared__ float Qs[64][17];
  __shared__ float Ks[64][17];
  const int t  = threadIdx.x;
  const int b  = blockIdx.z;
  const int i0 = blockIdx.x * 64;
  const int j0 = blockIdx.y * 64;
  const float* qb = q + (size_t)b * NQ_ * D_;
  const float* kb = k + (size_t)b * NK_ * D_;
  const int tx = t & 15, ty = t >> 4;
  float acc[4][4];
#pragma unroll
  for (int r = 0; r < 4; ++r)
#pragma unroll
    for (int c = 0; c < 4; ++c) acc[r][c] = 0.f;

  for (int k0 = 0; k0 < D_; k0 += 16) {
    const int ii = t & 15, rg = t >> 4;
#pragma unroll
    for (int p = 0; p < 4; ++p) {
      Qs[rg + 16 * p][ii] = qb[(size_t)(i0 + rg + 16 * p) * D_ + k0 + ii];
      Ks[rg + 16 * p][ii] = kb[(size_t)(j0 + rg + 16 * p) * D_ + k0 + ii];
    }
    __syncthreads();
#pragma unroll
    for (int kk = 0; kk < 16; ++kk) {
      float a[4], bb[4];
#pragma unroll
      for (int r = 0; r < 4; ++r) a[r] = Qs[ty + 16 * r][kk];
#pragma unroll
      for (int c = 0; c < 4; ++c) bb[c] = Ks[tx + 16 * c][kk];
#pragma unroll
      for (int r = 0; r < 4; ++r)
#pragma unroll
        for (int c = 0; c < 4; ++c) acc[r][c] += a[r] * bb[c];
    }
    __syncthreads();
  }
  const float scale = 0.0625f;  // 1/sqrt(256)
#pragma unroll
  for (int r = 0; r < 4; ++r) {
    const int i = i0 + ty + 16 * r;
#pragma unroll
    for (int c = 0; c < 4; ++c) {
      const int j = j0 + tx + 16 * c;
      S[((size_t)b * NQ_ + i) * NK_ + j] = acc[r][c] * scale;
    }
  }
}

// ---------------------------------------------------------------------------
// row softmax in place, one block per (b, i) row of 2048
// ---------------------------------------------------------------------------
__global__ __launch_bounds__(256) void softmax_kernel(float* __restrict__ S) {
  const size_t base = (size_t)blockIdx.x * NK_;
  const int t = threadIdx.x;
  float v[8];
#pragma unroll
  for (int p = 0; p < 8; ++p) v[p] = S[base + t + 256 * p];

  float m = v[0];
#pragma unroll
  for (int p = 1; p < 8; ++p) m = fmaxf(m, v[p]);
#pragma unroll
  for (int off = 1; off < 64; off <<= 1) m = fmaxf(m, __shfl_xor(m, off));

  __shared__ float redm[4];
  __shared__ float reds[4];
  const int wave = t >> 6, lane = t & 63;
  if (lane == 0) redm[wave] = m;
  __syncthreads();
  m = fmaxf(fmaxf(redm[0], redm[1]), fmaxf(redm[2], redm[3]));

  float s = 0.f;
#pragma unroll
  for (int p = 0; p < 8; ++p) {
    v[p] = __expf(v[p] - m);
    s += v[p];
  }
#pragma unroll
  for (int off = 1; off < 64; off <<= 1) s += __shfl_xor(s, off);
  if (lane == 0) reds[wave] = s;
  __syncthreads();
  s = reds[0] + reds[1] + reds[2] + reds[3];

  const float inv = 1.0f / s;
#pragma unroll
  for (int p = 0; p < 8; ++p) S[base + t + 256 * p] = v[p] * inv;
}

// ---------------------------------------------------------------------------
// out[b,i,d] = sum_j P[b,i,j] * V[b,j,d]      (V = original key input)
// ---------------------------------------------------------------------------
__global__ __launch_bounds__(256) void pv_kernel(const float* __restrict__ P,
                                                 const float* __restrict__ V,
                                                 float* __restrict__ out) {
  __shared__ float Ps[64][17];   // [i][j]
  __shared__ float Vs[16][65];   // [j][d]
  const int t  = threadIdx.x;
  const int b  = blockIdx.z;
  const int i0 = blockIdx.x * 64;
  const int d0 = blockIdx.y * 64;
  const int tx = t & 15, ty = t >> 4;
  float acc[4][4];
#pragma unroll
  for (int r = 0; r < 4; ++r)
#pragma unroll
    for (int c = 0; c < 4; ++c) acc[r][c] = 0.f;

  for (int j0 = 0; j0 < NK_; j0 += 16) {
    {
      const int jj = t & 15, ig = t >> 4;
#pragma unroll
      for (int p = 0; p < 4; ++p) {
        const int ii = ig + 16 * p;
        Ps[ii][jj] = P[((size_t)b * NQ_ + i0 + ii) * NK_ + j0 + jj];
      }
    }
    {
      const int dd = t & 63, jg = t >> 6;
#pragma unroll
      for (int p = 0; p < 4; ++p) {
        const int jj = jg * 4 + p;
        Vs[jj][dd] = V[((size_t)b * NK_ + j0 + jj) * D_ + d0 + dd];
      }
    }
    __syncthreads();
#pragma unroll
    for (int kk = 0; kk < 16; ++kk) {
      float a[4], bb[4];
#pragma unroll
      for (int r = 0; r < 4; ++r) a[r] = Ps[ty + 16 * r][kk];
#pragma unroll
      for (int c = 0; c < 4; ++c) bb[c] = Vs[kk][tx + 16 * c];
#pragma unroll
      for (int r = 0; r < 4; ++r)
#pragma unroll
        for (int c = 0; c < 4; ++c) acc[r][c] += a[r] * bb[c];
    }
    __syncthreads();
  }
#pragma unroll
  for (int r = 0; r < 4; ++r) {
    const int i = i0 + ty + 16 * r;
#pragma unroll
    for (int c = 0; c < 4; ++c) {
      const int d = d0 + tx + 16 * c;
      out[((size_t)b * NQ_ + i) * D_ + d] = acc[r][c];
    }
  }
}

extern "C" void kernel_launch(void* const* d_in, const int* in_sizes, int n_in,
                              void* d_out, int out_size, void* d_ws, size_t ws_size,
                              hipStream_t stream) {
  const float* query = (const float*)d_in[0];
  const float* key   = (const float*)d_in[1];
  const float* Wq    = (const float*)d_in[2];
  const float* bq    = (const float*)d_in[3];
  const float* Wk    = (const float*)d_in[4];
  const float* bk    = (const float*)d_in[5];
  float* out = (float*)d_out;

  char* ws = (char*)d_ws;
  float* qr = (float*)(ws);                       // 16 MB
  float* q  = (float*)(ws + ((size_t)16 << 20));  // 16 MB
  float* k  = (float*)(ws + ((size_t)32 << 20));  // 16 MB
  float* S  = (float*)(ws + ((size_t)48 << 20));  // 128 MB

  dim3 blk(256);
  // Re(FFT): rows 0..1087 directly (17 tiles), rest mirrored
  dft_kernel<<<dim3(17, D_ / 64, B_), blk, 0, stream>>>(query, qr);
  mirror_kernel<<<dim3(960, B_), blk, 0, stream>>>(qr);
  // projections
  proj_kernel<<<dim3(B_ * NQ_ / 64, D_ / 64), blk, 0, stream>>>(qr, Wq, bq, q);
  proj_kernel<<<dim3(B_ * NK_ / 64, D_ / 64), blk, 0, stream>>>(key, Wk, bk, k);
  // attention
  scores_kernel<<<dim3(NQ_ / 64, NK_ / 64, B_), blk, 0, stream>>>(q, k, S);
  softmax_kernel<<<dim3(B_ * NQ_), blk, 0, stream>>>(S);
  pv_kernel<<<dim3(NQ_ / 64, D_ / 64, B_), blk, 0, stream>>>(S, key, out);
}

// Round 2
// 673.475 us; speedup vs baseline: 1.6193x; 1.6193x over previous
//
#include <hip/hip_runtime.h>

#define B_ 8
#define NQ_ 2048
#define NK_ 2048
#define D_ 256

typedef __attribute__((ext_vector_type(8))) short bf16x8_t;
typedef __attribute__((ext_vector_type(4))) float f32x4_t;

static __device__ __forceinline__ unsigned short f2bf(float x) {
  unsigned int u = __float_as_uint(x);
  unsigned int r = (u + 0x7FFFu + ((u >> 16) & 1u)) >> 16;
  return (unsigned short)r;
}
static __device__ __forceinline__ float bf2f(unsigned short b) {
  return __uint_as_float(((unsigned int)b) << 16);
}

// ---------------------------------------------------------------------------
// qr[b,i,d] = sum_n cos(2*pi*i*n/2048) * query[b,n,d]   (Re of FFT along seq)
// rows 0..1087 computed; rest mirrored (Re symmetric for real input).
// ---------------------------------------------------------------------------
__global__ __launch_bounds__(256) void dft_kernel(const float* __restrict__ query,
                                                  float* __restrict__ qr) {
  __shared__ float cost[2048];
  __shared__ float Cs[64][17];
  __shared__ float Qs[16][65];
  const int t  = threadIdx.x;
  const int b  = blockIdx.z;
  const int i0 = blockIdx.x * 64;
  const int d0 = blockIdx.y * 64;

  for (int idx = t; idx < 2048; idx += 256)
    cost[idx] = __cosf((float)idx * (6.28318530717958647692f / 2048.0f));
  __syncthreads();

  const int tx = t & 15, ty = t >> 4;
  float acc[4][4];
#pragma unroll
  for (int r = 0; r < 4; ++r)
#pragma unroll
    for (int c = 0; c < 4; ++c) acc[r][c] = 0.f;

  for (int n0 = 0; n0 < NQ_; n0 += 16) {
    {
      const int dd = t & 63, ng = t >> 6;
#pragma unroll
      for (int p = 0; p < 4; ++p) {
        const int nn = ng * 4 + p;
        Qs[nn][dd] = query[((size_t)b * NQ_ + n0 + nn) * D_ + d0 + dd];
      }
    }
    {
      const int nn = t & 15, ig = t >> 4;
#pragma unroll
      for (int p = 0; p < 4; ++p) {
        const int ii = ig + 16 * p;
        Cs[ii][nn] = cost[((i0 + ii) * (n0 + nn)) & 2047];
      }
    }
    __syncthreads();
#pragma unroll
    for (int kk = 0; kk < 16; ++kk) {
      float a[4], bb[4];
#pragma unroll
      for (int r = 0; r < 4; ++r) a[r] = Cs[ty + 16 * r][kk];
#pragma unroll
      for (int c = 0; c < 4; ++c) bb[c] = Qs[kk][tx + 16 * c];
#pragma unroll
      for (int r = 0; r < 4; ++r)
#pragma unroll
        for (int c = 0; c < 4; ++c) acc[r][c] += a[r] * bb[c];
    }
    __syncthreads();
  }
#pragma unroll
  for (int r = 0; r < 4; ++r) {
    const int i = i0 + ty + 16 * r;
#pragma unroll
    for (int c = 0; c < 4; ++c) {
      const int d = d0 + tx + 16 * c;
      qr[((size_t)b * NQ_ + i) * D_ + d] = acc[r][c];
    }
  }
}

__global__ __launch_bounds__(256) void mirror_kernel(float* __restrict__ qr) {
  const int i = 1088 + blockIdx.x;
  const int b = blockIdx.y;
  const int src = 2048 - i;
  qr[((size_t)b * NQ_ + i) * D_ + threadIdx.x] =
      qr[((size_t)b * NQ_ + src) * D_ + threadIdx.x];
}

// ---------------------------------------------------------------------------
// y = x @ W.T + bias (f32 compute), epilogue emits split bf16: y_hi + y_lo
// ---------------------------------------------------------------------------
__global__ __launch_bounds__(256) void proj_split_kernel(const float* __restrict__ x,
                                                         const float* __restrict__ W,
                                                         const float* __restrict__ bias,
                                                         unsigned short* __restrict__ yh,
                                                         unsigned short* __restrict__ yl) {
  __shared__ float Xs[64][17];
  __shared__ float Ws[64][17];
  const int t  = threadIdx.x;
  const int m0 = blockIdx.x * 64;
  const int o0 = blockIdx.y * 64;
  const int tx = t & 15, ty = t >> 4;
  float acc[4][4];
#pragma unroll
  for (int r = 0; r < 4; ++r)
#pragma unroll
    for (int c = 0; c < 4; ++c) acc[r][c] = 0.f;

  for (int k0 = 0; k0 < D_; k0 += 16) {
    const int ii = t & 15, rg = t >> 4;
#pragma unroll
    for (int p = 0; p < 4; ++p) {
      Xs[rg + 16 * p][ii] = x[(size_t)(m0 + rg + 16 * p) * D_ + k0 + ii];
      Ws[rg + 16 * p][ii] = W[(size_t)(o0 + rg + 16 * p) * D_ + k0 + ii];
    }
    __syncthreads();
#pragma unroll
    for (int kk = 0; kk < 16; ++kk) {
      float a[4], bb[4];
#pragma unroll
      for (int r = 0; r < 4; ++r) a[r] = Xs[ty + 16 * r][kk];
#pragma unroll
      for (int c = 0; c < 4; ++c) bb[c] = Ws[tx + 16 * c][kk];
#pragma unroll
      for (int r = 0; r < 4; ++r)
#pragma unroll
        for (int c = 0; c < 4; ++c) acc[r][c] += a[r] * bb[c];
    }
    __syncthreads();
  }
#pragma unroll
  for (int r = 0; r < 4; ++r) {
    const int m = m0 + ty + 16 * r;
#pragma unroll
    for (int c = 0; c < 4; ++c) {
      const int o = o0 + tx + 16 * c;
      const float v = acc[r][c] + bias[o];
      const unsigned short hb = f2bf(v);
      yh[(size_t)m * D_ + o] = hb;
      yl[(size_t)m * D_ + o] = f2bf(v - bf2f(hb));
    }
  }
}

// ---------------------------------------------------------------------------
// Vt[b][d][j] = bf16(key[b][j][d])   (transpose for PV B-fragment reads)
// ---------------------------------------------------------------------------
__global__ __launch_bounds__(256) void vt_kernel(const float* __restrict__ key,
                                                 unsigned short* __restrict__ Vt) {
  __shared__ float lds[32][33];
  const int t  = threadIdx.x;
  const int j0 = blockIdx.x * 32;
  const int d0 = blockIdx.y * 32;
  const int b  = blockIdx.z;
#pragma unroll
  for (int p = 0; p < 4; ++p) {
    const int idx = t + 256 * p;
    const int dd = idx & 31, jj = idx >> 5;
    lds[jj][dd] = key[((size_t)b * NK_ + j0 + jj) * D_ + d0 + dd];
  }
  __syncthreads();
#pragma unroll
  for (int p = 0; p < 4; ++p) {
    const int idx = t + 256 * p;
    const int jj = idx & 31, dd = idx >> 5;
    Vt[((size_t)b * D_ + d0 + dd) * NK_ + j0 + jj] = f2bf(lds[jj][dd]);
  }
}

// ---------------------------------------------------------------------------
// S[b,i,j] = scale * sum_d q[b,i,d]*k[b,j,d]  -- split-bf16 3-MFMA emulation.
// Block: 128q x 128j, 4 waves of 64x64 (4x4 frags of 16x16x32), D chunks of 64.
// ---------------------------------------------------------------------------
__global__ __launch_bounds__(256, 2) void scores_mfma(const unsigned short* __restrict__ qh,
                                                      const unsigned short* __restrict__ ql,
                                                      const unsigned short* __restrict__ kh,
                                                      const unsigned short* __restrict__ kl,
                                                      float* __restrict__ S) {
  __shared__ __align__(16) unsigned short Qh[128][72];
  __shared__ __align__(16) unsigned short Ql[128][72];
  __shared__ __align__(16) unsigned short Kh[128][72];
  __shared__ __align__(16) unsigned short Kl[128][72];
  const int t = threadIdx.x;
  const int b = blockIdx.z;
  const int i0 = blockIdx.x * 128, j0 = blockIdx.y * 128;
  const int w = t >> 6, lane = t & 63, quad = lane >> 4, l16 = lane & 15;
  const int wq = w & 1, wj = w >> 1;

  f32x4_t acc[4][4];
#pragma unroll
  for (int a = 0; a < 4; ++a)
#pragma unroll
    for (int c = 0; c < 4; ++c) acc[a][c] = (f32x4_t)0.f;

  const size_t qbase = ((size_t)b * NQ_ + i0) * D_;
  const size_t kbase = ((size_t)b * NK_ + j0) * D_;

  for (int c0 = 0; c0 < D_; c0 += 64) {
#pragma unroll
    for (int it = 0; it < 4; ++it) {
      const int unit = t + 256 * it;
      const int row = unit >> 3, u = (unit & 7) * 8;
      const size_t go = (size_t)row * D_ + c0 + u;
      *(uint4*)&Qh[row][u] = *(const uint4*)&qh[qbase + go];
      *(uint4*)&Ql[row][u] = *(const uint4*)&ql[qbase + go];
      *(uint4*)&Kh[row][u] = *(const uint4*)&kh[kbase + go];
      *(uint4*)&Kl[row][u] = *(const uint4*)&kl[kbase + go];
    }
    __syncthreads();
#pragma unroll
    for (int ks = 0; ks < 2; ++ks) {
      const int dcol = ks * 32 + quad * 8;
      bf16x8_t ah[4], al[4], bh[4], bl[4];
#pragma unroll
      for (int x = 0; x < 4; ++x) {
        ah[x] = *(const bf16x8_t*)&Qh[wq * 64 + x * 16 + l16][dcol];
        al[x] = *(const bf16x8_t*)&Ql[wq * 64 + x * 16 + l16][dcol];
        bh[x] = *(const bf16x8_t*)&Kh[wj * 64 + x * 16 + l16][dcol];
        bl[x] = *(const bf16x8_t*)&Kl[wj * 64 + x * 16 + l16][dcol];
      }
#pragma unroll
      for (int at = 0; at < 4; ++at)
#pragma unroll
        for (int jt = 0; jt < 4; ++jt) {
          acc[at][jt] = __builtin_amdgcn_mfma_f32_16x16x32_bf16(ah[at], bh[jt], acc[at][jt], 0, 0, 0);
          acc[at][jt] = __builtin_amdgcn_mfma_f32_16x16x32_bf16(ah[at], bl[jt], acc[at][jt], 0, 0, 0);
          acc[at][jt] = __builtin_amdgcn_mfma_f32_16x16x32_bf16(al[at], bh[jt], acc[at][jt], 0, 0, 0);
        }
    }
    __syncthreads();
  }
  const float scale = 0.0625f;
#pragma unroll
  for (int at = 0; at < 4; ++at) {
#pragma unroll
    for (int jt = 0; jt < 4; ++jt) {
      const int j = j0 + wj * 64 + jt * 16 + l16;
#pragma unroll
      for (int r = 0; r < 4; ++r) {
        const int i = i0 + wq * 64 + at * 16 + quad * 4 + r;
        S[((size_t)b * NQ_ + i) * NK_ + j] = acc[at][jt][r] * scale;
      }
    }
  }
}

// ---------------------------------------------------------------------------
// row softmax in place (f32), one block per row
// ---------------------------------------------------------------------------
__global__ __launch_bounds__(256) void softmax_kernel(float* __restrict__ S) {
  const size_t base = (size_t)blockIdx.x * NK_;
  const int t = threadIdx.x;
  float v[8];
#pragma unroll
  for (int p = 0; p < 8; ++p) v[p] = S[base + t + 256 * p];

  float m = v[0];
#pragma unroll
  for (int p = 1; p < 8; ++p) m = fmaxf(m, v[p]);
#pragma unroll
  for (int off = 1; off < 64; off <<= 1) m = fmaxf(m, __shfl_xor(m, off));

  __shared__ float redm[4];
  __shared__ float reds[4];
  const int wave = t >> 6, lane = t & 63;
  if (lane == 0) redm[wave] = m;
  __syncthreads();
  m = fmaxf(fmaxf(redm[0], redm[1]), fmaxf(redm[2], redm[3]));

  float s = 0.f;
#pragma unroll
  for (int p = 0; p < 8; ++p) {
    v[p] = __expf(v[p] - m);
    s += v[p];
  }
#pragma unroll
  for (int off = 1; off < 64; off <<= 1) s += __shfl_xor(s, off);
  if (lane == 0) reds[wave] = s;
  __syncthreads();
  s = reds[0] + reds[1] + reds[2] + reds[3];

  const float inv = 1.0f / s;
#pragma unroll
  for (int p = 0; p < 8; ++p) S[base + t + 256 * p] = v[p] * inv;
}

// ---------------------------------------------------------------------------
// out[m,d] = sum_j P[m,j] * V[j,d] -- bf16 MFMA. P staged f32->bf16 in LDS.
// Block: 128m x 128d, 4 waves of 64x64, NK chunks of 64.
// ---------------------------------------------------------------------------
__global__ __launch_bounds__(256, 4) void pv_mfma(const float* __restrict__ P,
                                                  const unsigned short* __restrict__ Vt,
                                                  float* __restrict__ out) {
  __shared__ __align__(16) unsigned short Ps[128][72];
  __shared__ __align__(16) unsigned short Vs[128][72];
  const int t = threadIdx.x;
  const int m0 = blockIdx.x * 128;       // global row (includes batch)
  const int d0 = blockIdx.y * 128;
  const int b  = blockIdx.x >> 4;        // 16 row-blocks per batch
  const int w = t >> 6, lane = t & 63, quad = lane >> 4, l16 = lane & 15;
  const int wq = w & 1, wd = w >> 1;

  f32x4_t acc[4][4];
#pragma unroll
  for (int a = 0; a < 4; ++a)
#pragma unroll
    for (int c = 0; c < 4; ++c) acc[a][c] = (f32x4_t)0.f;

  for (int jc = 0; jc < NK_; jc += 64) {
    // stage P tile (f32 -> bf16)
#pragma unroll
    for (int it = 0; it < 8; ++it) {
      const int unit = t + 256 * it;
      const int row = unit >> 4, u = (unit & 15) * 4;
      const float4 v = *(const float4*)&P[((size_t)(m0 + row)) * NK_ + jc + u];
      unsigned int lo = (unsigned int)f2bf(v.x) | ((unsigned int)f2bf(v.y) << 16);
      unsigned int hi = (unsigned int)f2bf(v.z) | ((unsigned int)f2bf(v.w) << 16);
      uint2 pk; pk.x = lo; pk.y = hi;
      *(uint2*)&Ps[row][u] = pk;
    }
    // stage Vt tile (bf16, already [d][j])
#pragma unroll
    for (int it = 0; it < 4; ++it) {
      const int unit = t + 256 * it;
      const int row = unit >> 3, u = (unit & 7) * 8;
      *(uint4*)&Vs[row][u] = *(const uint4*)&Vt[((size_t)b * D_ + d0 + row) * NK_ + jc + u];
    }
    __syncthreads();
#pragma unroll
    for (int ks = 0; ks < 2; ++ks) {
      const int jcol = ks * 32 + quad * 8;
      bf16x8_t a[4], bv[4];
#pragma unroll
      for (int x = 0; x < 4; ++x) {
        a[x]  = *(const bf16x8_t*)&Ps[wq * 64 + x * 16 + l16][jcol];
        bv[x] = *(const bf16x8_t*)&Vs[wd * 64 + x * 16 + l16][jcol];
      }
#pragma unroll
      for (int at = 0; at < 4; ++at)
#pragma unroll
        for (int bt = 0; bt < 4; ++bt)
          acc[at][bt] = __builtin_amdgcn_mfma_f32_16x16x32_bf16(a[at], bv[bt], acc[at][bt], 0, 0, 0);
    }
    __syncthreads();
  }
#pragma unroll
  for (int at = 0; at < 4; ++at) {
#pragma unroll
    for (int bt = 0; bt < 4; ++bt) {
      const int d = d0 + wd * 64 + bt * 16 + l16;
#pragma unroll
      for (int r = 0; r < 4; ++r) {
        const int m = m0 + wq * 64 + at * 16 + quad * 4 + r;
        out[(size_t)m * D_ + d] = acc[at][bt][r];
      }
    }
  }
}

extern "C" void kernel_launch(void* const* d_in, const int* in_sizes, int n_in,
                              void* d_out, int out_size, void* d_ws, size_t ws_size,
                              hipStream_t stream) {
  const float* query = (const float*)d_in[0];
  const float* key   = (const float*)d_in[1];
  const float* Wq    = (const float*)d_in[2];
  const float* bq    = (const float*)d_in[3];
  const float* Wk    = (const float*)d_in[4];
  const float* bk    = (const float*)d_in[5];
  float* out = (float*)d_out;

  char* ws = (char*)d_ws;
  // 8 MB each bf16 [16384][256]
  unsigned short* q_hi = (unsigned short*)(ws);
  unsigned short* q_lo = (unsigned short*)(ws + ((size_t)8 << 20));
  unsigned short* k_hi = (unsigned short*)(ws + ((size_t)16 << 20));
  unsigned short* k_lo = (unsigned short*)(ws + ((size_t)24 << 20));
  unsigned short* Vt   = (unsigned short*)(ws + ((size_t)32 << 20));  // 8 MB
  float* S  = (float*)(ws + ((size_t)40 << 20));                      // 128 MB
  float* qr = (float*)(ws + ((size_t)40 << 20));                      // 16 MB, dead before S written

  dim3 blk(256);
  dft_kernel<<<dim3(17, D_ / 64, B_), blk, 0, stream>>>(query, qr);
  mirror_kernel<<<dim3(960, B_), blk, 0, stream>>>(qr);
  proj_split_kernel<<<dim3(B_ * NQ_ / 64, D_ / 64), blk, 0, stream>>>(qr, Wq, bq, q_hi, q_lo);
  proj_split_kernel<<<dim3(B_ * NK_ / 64, D_ / 64), blk, 0, stream>>>(key, Wk, bk, k_hi, k_lo);
  vt_kernel<<<dim3(NK_ / 32, D_ / 32, B_), blk, 0, stream>>>(key, Vt);
  scores_mfma<<<dim3(NQ_ / 128, NK_ / 128, B_), blk, 0, stream>>>(q_hi, q_lo, k_hi, k_lo, S);
  softmax_kernel<<<dim3(B_ * NQ_), blk, 0, stream>>>(S);
  pv_mfma<<<dim3(B_ * NQ_ / 128, D_ / 128), blk, 0, stream>>>(S, Vt, out);
}

// Round 3
// 445.985 us; speedup vs baseline: 2.4453x; 1.5101x over previous
//
#include <hip/hip_runtime.h>

#define B_ 8
#define NQ_ 2048
#define NK_ 2048
#define D_ 256

typedef __attribute__((ext_vector_type(8))) short bf16x8_t;
typedef __attribute__((ext_vector_type(4))) float f32x4_t;

static __device__ __forceinline__ unsigned short f2bf(float x) {
  unsigned int u = __float_as_uint(x);
  unsigned int r = (u + 0x7FFFu + ((u >> 16) & 1u)) >> 16;
  return (unsigned short)r;
}
static __device__ __forceinline__ float bf2f(unsigned short b) {
  return __uint_as_float(((unsigned int)b) << 16);
}

// ---------------------------------------------------------------------------
// generic f32 -> split bf16 (hi + lo)
// ---------------------------------------------------------------------------
__global__ __launch_bounds__(256) void split_kernel(const float* __restrict__ x,
                                                    unsigned short* __restrict__ xh,
                                                    unsigned short* __restrict__ xl,
                                                    int n) {
  const int i = blockIdx.x * 256 + threadIdx.x;
  if (i < n) {
    const float v = x[i];
    const unsigned short hb = f2bf(v);
    xh[i] = hb;
    xl[i] = f2bf(v - bf2f(hb));
  }
}

// ---------------------------------------------------------------------------
// C[i][n] = cos(2*pi*(i*n mod 2048)/2048), i in [0,1152), split bf16
// ---------------------------------------------------------------------------
__global__ __launch_bounds__(256) void cos_split_kernel(unsigned short* __restrict__ Ch,
                                                        unsigned short* __restrict__ Cl) {
  const int idx = blockIdx.x * 256 + threadIdx.x;   // i*2048 + n
  const int i = idx >> 11, n = idx & 2047;
  const int m = (i * n) & 2047;
  const float c = cosf((float)m * 0.0030679615757712823f);  // 2*pi/2048
  const unsigned short hb = f2bf(c);
  Ch[idx] = hb;
  Cl[idx] = f2bf(c - bf2f(hb));
}

// ---------------------------------------------------------------------------
// Qt[b][d][n] = split(query[b][n][d])  (transpose + split)
// ---------------------------------------------------------------------------
__global__ __launch_bounds__(256) void qt_split_kernel(const float* __restrict__ q,
                                                       unsigned short* __restrict__ Qth,
                                                       unsigned short* __restrict__ Qtl) {
  __shared__ float lds[32][33];
  const int t  = threadIdx.x;
  const int n0 = blockIdx.x * 32;
  const int d0 = blockIdx.y * 32;
  const int b  = blockIdx.z;
#pragma unroll
  for (int p = 0; p < 4; ++p) {
    const int idx = t + 256 * p;
    const int dd = idx & 31, nn = idx >> 5;
    lds[nn][dd] = q[((size_t)b * NQ_ + n0 + nn) * D_ + d0 + dd];
  }
  __syncthreads();
#pragma unroll
  for (int p = 0; p < 4; ++p) {
    const int idx = t + 256 * p;
    const int nn = idx & 31, dd = idx >> 5;
    const float v = lds[nn][dd];
    const unsigned short hb = f2bf(v);
    const size_t o = ((size_t)b * D_ + d0 + dd) * NQ_ + n0 + nn;
    Qth[o] = hb;
    Qtl[o] = f2bf(v - bf2f(hb));
  }
}

// ---------------------------------------------------------------------------
// Vt[b][d][j] = keyh[b][j][d]   (bf16 transpose)
// ---------------------------------------------------------------------------
__global__ __launch_bounds__(256) void vt_bf16_kernel(const unsigned short* __restrict__ keyh,
                                                      unsigned short* __restrict__ Vt) {
  __shared__ unsigned short lds[32][40];
  const int t  = threadIdx.x;
  const int j0 = blockIdx.x * 32;
  const int d0 = blockIdx.y * 32;
  const int b  = blockIdx.z;
#pragma unroll
  for (int p = 0; p < 4; ++p) {
    const int idx = t + 256 * p;
    const int dd = idx & 31, jj = idx >> 5;
    lds[jj][dd] = keyh[((size_t)b * NK_ + j0 + jj) * D_ + d0 + dd];
  }
  __syncthreads();
#pragma unroll
  for (int p = 0; p < 4; ++p) {
    const int idx = t + 256 * p;
    const int jj = idx & 31, dd = idx >> 5;
    Vt[((size_t)b * D_ + d0 + dd) * NK_ + j0 + jj] = lds[jj][dd];
  }
}

// ---------------------------------------------------------------------------
// qr[b][i][d] = sum_n C[i][n] * query[b][n][d] -- split-bf16 3-MFMA.
// Block: 128i x 128d, 4 waves of 64x64. K=2048 in chunks of 64.
// Epilogue: split bf16 out (qrh/qrl).
// ---------------------------------------------------------------------------
__global__ __launch_bounds__(256, 2) void dft_mfma(const unsigned short* __restrict__ Ch,
                                                   const unsigned short* __restrict__ Cl,
                                                   const unsigned short* __restrict__ Qth,
                                                   const unsigned short* __restrict__ Qtl,
                                                   unsigned short* __restrict__ qrh,
                                                   unsigned short* __restrict__ qrl) {
  __shared__ __align__(16) unsigned short Ah[128][72];
  __shared__ __align__(16) unsigned short Al[128][72];
  __shared__ __align__(16) unsigned short Bh[128][72];
  __shared__ __align__(16) unsigned short Bl[128][72];
  const int t = threadIdx.x;
  const int b = blockIdx.z;
  const int i0 = blockIdx.x * 128, d0 = blockIdx.y * 128;
  const int w = t >> 6, lane = t & 63, quad = lane >> 4, l16 = lane & 15;
  const int wq = w & 1, wj = w >> 1;

  f32x4_t acc[4][4];
#pragma unroll
  for (int a = 0; a < 4; ++a)
#pragma unroll
    for (int c = 0; c < 4; ++c) acc[a][c] = (f32x4_t)0.f;

  const size_t abase = (size_t)i0 * 2048;
  const size_t bbase = ((size_t)b * D_ + d0) * 2048;

  for (int c0 = 0; c0 < 2048; c0 += 64) {
#pragma unroll
    for (int it = 0; it < 4; ++it) {
      const int unit = t + 256 * it;
      const int row = unit >> 3, u = (unit & 7) * 8;
      const size_t go = (size_t)row * 2048 + c0 + u;
      *(uint4*)&Ah[row][u] = *(const uint4*)&Ch[abase + go];
      *(uint4*)&Al[row][u] = *(const uint4*)&Cl[abase + go];
      *(uint4*)&Bh[row][u] = *(const uint4*)&Qth[bbase + go];
      *(uint4*)&Bl[row][u] = *(const uint4*)&Qtl[bbase + go];
    }
    __syncthreads();
#pragma unroll
    for (int ks = 0; ks < 2; ++ks) {
      const int dcol = ks * 32 + quad * 8;
      bf16x8_t ah[4], al[4], bh[4], bl[4];
#pragma unroll
      for (int x = 0; x < 4; ++x) {
        ah[x] = *(const bf16x8_t*)&Ah[wq * 64 + x * 16 + l16][dcol];
        al[x] = *(const bf16x8_t*)&Al[wq * 64 + x * 16 + l16][dcol];
        bh[x] = *(const bf16x8_t*)&Bh[wj * 64 + x * 16 + l16][dcol];
        bl[x] = *(const bf16x8_t*)&Bl[wj * 64 + x * 16 + l16][dcol];
      }
#pragma unroll
      for (int at = 0; at < 4; ++at)
#pragma unroll
        for (int jt = 0; jt < 4; ++jt) {
          acc[at][jt] = __builtin_amdgcn_mfma_f32_16x16x32_bf16(ah[at], bh[jt], acc[at][jt], 0, 0, 0);
          acc[at][jt] = __builtin_amdgcn_mfma_f32_16x16x32_bf16(ah[at], bl[jt], acc[at][jt], 0, 0, 0);
          acc[at][jt] = __builtin_amdgcn_mfma_f32_16x16x32_bf16(al[at], bh[jt], acc[at][jt], 0, 0, 0);
        }
    }
    __syncthreads();
  }
#pragma unroll
  for (int at = 0; at < 4; ++at) {
#pragma unroll
    for (int jt = 0; jt < 4; ++jt) {
      const int d = d0 + wj * 64 + jt * 16 + l16;
#pragma unroll
      for (int r = 0; r < 4; ++r) {
        const int i = i0 + wq * 64 + at * 16 + quad * 4 + r;
        const float v = acc[at][jt][r];
        const unsigned short hb = f2bf(v);
        const size_t o = ((size_t)b * NQ_ + i) * D_ + d;
        qrh[o] = hb;
        qrl[o] = f2bf(v - bf2f(hb));
      }
    }
  }
}

// mirror rows 1088..2047 <- row (2048-i), both hi and lo
__global__ __launch_bounds__(256) void mirror2_kernel(unsigned short* __restrict__ qrh,
                                                      unsigned short* __restrict__ qrl) {
  const int i = 1088 + blockIdx.x;
  const int b = blockIdx.y;
  const int src = 2048 - i;
  const size_t dsto = ((size_t)b * NQ_ + i) * D_ + threadIdx.x;
  const size_t srco = ((size_t)b * NQ_ + src) * D_ + threadIdx.x;
  qrh[dsto] = qrh[srco];
  qrl[dsto] = qrl[srco];
}

// ---------------------------------------------------------------------------
// y = x @ W.T + bias -- split-bf16 3-MFMA, split epilogue.
// Block: 128m x 128o, 4 waves of 64x64. K=256 in chunks of 64.
// ---------------------------------------------------------------------------
__global__ __launch_bounds__(256, 2) void proj_mfma(const unsigned short* __restrict__ xh,
                                                    const unsigned short* __restrict__ xl,
                                                    const unsigned short* __restrict__ Wh,
                                                    const unsigned short* __restrict__ Wl,
                                                    const float* __restrict__ bias,
                                                    unsigned short* __restrict__ yh,
                                                    unsigned short* __restrict__ yl) {
  __shared__ __align__(16) unsigned short Xh[128][72];
  __shared__ __align__(16) unsigned short Xl[128][72];
  __shared__ __align__(16) unsigned short Bh[128][72];
  __shared__ __align__(16) unsigned short Bl[128][72];
  const int t = threadIdx.x;
  const int m0 = blockIdx.x * 128, o0 = blockIdx.y * 128;
  const int w = t >> 6, lane = t & 63, quad = lane >> 4, l16 = lane & 15;
  const int wq = w & 1, wj = w >> 1;

  f32x4_t acc[4][4];
#pragma unroll
  for (int a = 0; a < 4; ++a)
#pragma unroll
    for (int c = 0; c < 4; ++c) acc[a][c] = (f32x4_t)0.f;

  const size_t xbase = (size_t)m0 * D_;
  const size_t wbase = (size_t)o0 * D_;

  for (int c0 = 0; c0 < D_; c0 += 64) {
#pragma unroll
    for (int it = 0; it < 4; ++it) {
      const int unit = t + 256 * it;
      const int row = unit >> 3, u = (unit & 7) * 8;
      const size_t go = (size_t)row * D_ + c0 + u;
      *(uint4*)&Xh[row][u] = *(const uint4*)&xh[xbase + go];
      *(uint4*)&Xl[row][u] = *(const uint4*)&xl[xbase + go];
      *(uint4*)&Bh[row][u] = *(const uint4*)&Wh[wbase + go];
      *(uint4*)&Bl[row][u] = *(const uint4*)&Wl[wbase + go];
    }
    __syncthreads();
#pragma unroll
    for (int ks = 0; ks < 2; ++ks) {
      const int dcol = ks * 32 + quad * 8;
      bf16x8_t ah[4], al[4], bh[4], bl[4];
#pragma unroll
      for (int x = 0; x < 4; ++x) {
        ah[x] = *(const bf16x8_t*)&Xh[wq * 64 + x * 16 + l16][dcol];
        al[x] = *(const bf16x8_t*)&Xl[wq * 64 + x * 16 + l16][dcol];
        bh[x] = *(const bf16x8_t*)&Bh[wj * 64 + x * 16 + l16][dcol];
        bl[x] = *(const bf16x8_t*)&Bl[wj * 64 + x * 16 + l16][dcol];
      }
#pragma unroll
      for (int at = 0; at < 4; ++at)
#pragma unroll
        for (int jt = 0; jt < 4; ++jt) {
          acc[at][jt] = __builtin_amdgcn_mfma_f32_16x16x32_bf16(ah[at], bh[jt], acc[at][jt], 0, 0, 0);
          acc[at][jt] = __builtin_amdgcn_mfma_f32_16x16x32_bf16(ah[at], bl[jt], acc[at][jt], 0, 0, 0);
          acc[at][jt] = __builtin_amdgcn_mfma_f32_16x16x32_bf16(al[at], bh[jt], acc[at][jt], 0, 0, 0);
        }
    }
    __syncthreads();
  }
#pragma unroll
  for (int at = 0; at < 4; ++at) {
#pragma unroll
    for (int jt = 0; jt < 4; ++jt) {
      const int o = o0 + wj * 64 + jt * 16 + l16;
      const float bv = bias[o];
#pragma unroll
      for (int r = 0; r < 4; ++r) {
        const int m = m0 + wq * 64 + at * 16 + quad * 4 + r;
        const float v = acc[at][jt][r] + bv;
        const unsigned short hb = f2bf(v);
        yh[(size_t)m * D_ + o] = hb;
        yl[(size_t)m * D_ + o] = f2bf(v - bf2f(hb));
      }
    }
  }
}

// ---------------------------------------------------------------------------
// S[b,i,j] = scale * sum_d q.k  -- split-bf16 3-MFMA (verified round 2)
// ---------------------------------------------------------------------------
__global__ __launch_bounds__(256, 2) void scores_mfma(const unsigned short* __restrict__ qh,
                                                      const unsigned short* __restrict__ ql,
                                                      const unsigned short* __restrict__ kh,
                                                      const unsigned short* __restrict__ kl,
                                                      float* __restrict__ S) {
  __shared__ __align__(16) unsigned short Qh[128][72];
  __shared__ __align__(16) unsigned short Ql[128][72];
  __shared__ __align__(16) unsigned short Kh[128][72];
  __shared__ __align__(16) unsigned short Kl[128][72];
  const int t = threadIdx.x;
  const int b = blockIdx.z;
  const int i0 = blockIdx.x * 128, j0 = blockIdx.y * 128;
  const int w = t >> 6, lane = t & 63, quad = lane >> 4, l16 = lane & 15;
  const int wq = w & 1, wj = w >> 1;

  f32x4_t acc[4][4];
#pragma unroll
  for (int a = 0; a < 4; ++a)
#pragma unroll
    for (int c = 0; c < 4; ++c) acc[a][c] = (f32x4_t)0.f;

  const size_t qbase = ((size_t)b * NQ_ + i0) * D_;
  const size_t kbase = ((size_t)b * NK_ + j0) * D_;

  for (int c0 = 0; c0 < D_; c0 += 64) {
#pragma unroll
    for (int it = 0; it < 4; ++it) {
      const int unit = t + 256 * it;
      const int row = unit >> 3, u = (unit & 7) * 8;
      const size_t go = (size_t)row * D_ + c0 + u;
      *(uint4*)&Qh[row][u] = *(const uint4*)&qh[qbase + go];
      *(uint4*)&Ql[row][u] = *(const uint4*)&ql[qbase + go];
      *(uint4*)&Kh[row][u] = *(const uint4*)&kh[kbase + go];
      *(uint4*)&Kl[row][u] = *(const uint4*)&kl[kbase + go];
    }
    __syncthreads();
#pragma unroll
    for (int ks = 0; ks < 2; ++ks) {
      const int dcol = ks * 32 + quad * 8;
      bf16x8_t ah[4], al[4], bh[4], bl[4];
#pragma unroll
      for (int x = 0; x < 4; ++x) {
        ah[x] = *(const bf16x8_t*)&Qh[wq * 64 + x * 16 + l16][dcol];
        al[x] = *(const bf16x8_t*)&Ql[wq * 64 + x * 16 + l16][dcol];
        bh[x] = *(const bf16x8_t*)&Kh[wj * 64 + x * 16 + l16][dcol];
        bl[x] = *(const bf16x8_t*)&Kl[wj * 64 + x * 16 + l16][dcol];
      }
#pragma unroll
      for (int at = 0; at < 4; ++at)
#pragma unroll
        for (int jt = 0; jt < 4; ++jt) {
          acc[at][jt] = __builtin_amdgcn_mfma_f32_16x16x32_bf16(ah[at], bh[jt], acc[at][jt], 0, 0, 0);
          acc[at][jt] = __builtin_amdgcn_mfma_f32_16x16x32_bf16(ah[at], bl[jt], acc[at][jt], 0, 0, 0);
          acc[at][jt] = __builtin_amdgcn_mfma_f32_16x16x32_bf16(al[at], bh[jt], acc[at][jt], 0, 0, 0);
        }
    }
    __syncthreads();
  }
  const float scale = 0.0625f;
#pragma unroll
  for (int at = 0; at < 4; ++at) {
#pragma unroll
    for (int jt = 0; jt < 4; ++jt) {
      const int j = j0 + wj * 64 + jt * 16 + l16;
#pragma unroll
      for (int r = 0; r < 4; ++r) {
        const int i = i0 + wq * 64 + at * 16 + quad * 4 + r;
        S[((size_t)b * NQ_ + i) * NK_ + j] = acc[at][jt][r] * scale;
      }
    }
  }
}

// ---------------------------------------------------------------------------
// row softmax in place (f32)
// ---------------------------------------------------------------------------
__global__ __launch_bounds__(256) void softmax_kernel(float* __restrict__ S) {
  const size_t base = (size_t)blockIdx.x * NK_;
  const int t = threadIdx.x;
  float v[8];
#pragma unroll
  for (int p = 0; p < 8; ++p) v[p] = S[base + t + 256 * p];

  float m = v[0];
#pragma unroll
  for (int p = 1; p < 8; ++p) m = fmaxf(m, v[p]);
#pragma unroll
  for (int off = 1; off < 64; off <<= 1) m = fmaxf(m, __shfl_xor(m, off));

  __shared__ float redm[4];
  __shared__ float reds[4];
  const int wave = t >> 6, lane = t & 63;
  if (lane == 0) redm[wave] = m;
  __syncthreads();
  m = fmaxf(fmaxf(redm[0], redm[1]), fmaxf(redm[2], redm[3]));

  float s = 0.f;
#pragma unroll
  for (int p = 0; p < 8; ++p) {
    v[p] = __expf(v[p] - m);
    s += v[p];
  }
#pragma unroll
  for (int off = 1; off < 64; off <<= 1) s += __shfl_xor(s, off);
  if (lane == 0) reds[wave] = s;
  __syncthreads();
  s = reds[0] + reds[1] + reds[2] + reds[3];

  const float inv = 1.0f / s;
#pragma unroll
  for (int p = 0; p < 8; ++p) S[base + t + 256 * p] = v[p] * inv;
}

// ---------------------------------------------------------------------------
// out[m,d] = sum_j P[m,j] * V[j,d] -- bf16 MFMA (verified round 2)
// ---------------------------------------------------------------------------
__global__ __launch_bounds__(256, 4) void pv_mfma(const float* __restrict__ P,
                                                  const unsigned short* __restrict__ Vt,
                                                  float* __restrict__ out) {
  __shared__ __align__(16) unsigned short Ps[128][72];
  __shared__ __align__(16) unsigned short Vs[128][72];
  const int t = threadIdx.x;
  const int m0 = blockIdx.x * 128;
  const int d0 = blockIdx.y * 128;
  const int b  = blockIdx.x >> 4;
  const int w = t >> 6, lane = t & 63, quad = lane >> 4, l16 = lane & 15;
  const int wq = w & 1, wd = w >> 1;

  f32x4_t acc[4][4];
#pragma unroll
  for (int a = 0; a < 4; ++a)
#pragma unroll
    for (int c = 0; c < 4; ++c) acc[a][c] = (f32x4_t)0.f;

  for (int jc = 0; jc < NK_; jc += 64) {
#pragma unroll
    for (int it = 0; it < 8; ++it) {
      const int unit = t + 256 * it;
      const int row = unit >> 4, u = (unit & 15) * 4;
      const float4 v = *(const float4*)&P[((size_t)(m0 + row)) * NK_ + jc + u];
      unsigned int lo = (unsigned int)f2bf(v.x) | ((unsigned int)f2bf(v.y) << 16);
      unsigned int hi = (unsigned int)f2bf(v.z) | ((unsigned int)f2bf(v.w) << 16);
      uint2 pk; pk.x = lo; pk.y = hi;
      *(uint2*)&Ps[row][u] = pk;
    }
#pragma unroll
    for (int it = 0; it < 4; ++it) {
      const int unit = t + 256 * it;
      const int row = unit >> 3, u = (unit & 7) * 8;
      *(uint4*)&Vs[row][u] = *(const uint4*)&Vt[((size_t)b * D_ + d0 + row) * NK_ + jc + u];
    }
    __syncthreads();
#pragma unroll
    for (int ks = 0; ks < 2; ++ks) {
      const int jcol = ks * 32 + quad * 8;
      bf16x8_t a[4], bv[4];
#pragma unroll
      for (int x = 0; x < 4; ++x) {
        a[x]  = *(const bf16x8_t*)&Ps[wq * 64 + x * 16 + l16][jcol];
        bv[x] = *(const bf16x8_t*)&Vs[wd * 64 + x * 16 + l16][jcol];
      }
#pragma unroll
      for (int at = 0; at < 4; ++at)
#pragma unroll
        for (int bt = 0; bt < 4; ++bt)
          acc[at][bt] = __builtin_amdgcn_mfma_f32_16x16x32_bf16(a[at], bv[bt], acc[at][bt], 0, 0, 0);
    }
    __syncthreads();
  }
#pragma unroll
  for (int at = 0; at < 4; ++at) {
#pragma unroll
    for (int bt = 0; bt < 4; ++bt) {
      const int d = d0 + wd * 64 + bt * 16 + l16;
#pragma unroll
      for (int r = 0; r < 4; ++r) {
        const int m = m0 + wq * 64 + at * 16 + quad * 4 + r;
        out[(size_t)m * D_ + d] = acc[at][bt][r];
      }
    }
  }
}

extern "C" void kernel_launch(void* const* d_in, const int* in_sizes, int n_in,
                              void* d_out, int out_size, void* d_ws, size_t ws_size,
                              hipStream_t stream) {
  const float* query = (const float*)d_in[0];
  const float* key   = (const float*)d_in[1];
  const float* Wq    = (const float*)d_in[2];
  const float* bq    = (const float*)d_in[3];
  const float* Wk    = (const float*)d_in[4];
  const float* bk    = (const float*)d_in[5];
  float* out = (float*)d_out;

  char* ws = (char*)d_ws;
  const size_t MB = (size_t)1 << 20;
  // persistent through scores/pv:
  unsigned short* qh = (unsigned short*)(ws);            // 8 MB
  unsigned short* ql = (unsigned short*)(ws + 8 * MB);   // 8 MB
  unsigned short* kh = (unsigned short*)(ws + 16 * MB);  // 8 MB
  unsigned short* kl = (unsigned short*)(ws + 24 * MB);  // 8 MB
  unsigned short* Vt = (unsigned short*)(ws + 32 * MB);  // 8 MB
  float* S = (float*)(ws + 40 * MB);                     // 128 MB -> 168 total
  // transient, packed inside the S region (dead before scores_mfma writes S):
  unsigned short* Ch   = (unsigned short*)(ws + 40 * MB);             // 4.5 MB
  unsigned short* Cl   = (unsigned short*)(ws + 45 * MB);             // 4.5 MB
  unsigned short* Qth  = (unsigned short*)(ws + 50 * MB);             // 8 MB
  unsigned short* Qtl  = (unsigned short*)(ws + 58 * MB);             // 8 MB
  unsigned short* qrh  = (unsigned short*)(ws + 66 * MB);             // 8 MB
  unsigned short* qrl  = (unsigned short*)(ws + 74 * MB);             // 8 MB
  unsigned short* keyh = (unsigned short*)(ws + 82 * MB);             // 8 MB
  unsigned short* keyl = (unsigned short*)(ws + 90 * MB);             // 8 MB
  unsigned short* Wqh  = (unsigned short*)(ws + 98 * MB);             // 128 KB
  unsigned short* Wql  = (unsigned short*)(ws + 98 * MB + 256 * 1024);
  unsigned short* Wkh  = (unsigned short*)(ws + 98 * MB + 512 * 1024);
  unsigned short* Wkl  = (unsigned short*)(ws + 98 * MB + 768 * 1024);

  dim3 blk(256);
  // splits
  split_kernel<<<B_ * NK_ * D_ / 256, blk, 0, stream>>>(key, keyh, keyl, B_ * NK_ * D_);
  split_kernel<<<D_ * D_ / 256, blk, 0, stream>>>(Wq, Wqh, Wql, D_ * D_);
  split_kernel<<<D_ * D_ / 256, blk, 0, stream>>>(Wk, Wkh, Wkl, D_ * D_);
  cos_split_kernel<<<1152 * 2048 / 256, blk, 0, stream>>>(Ch, Cl);
  qt_split_kernel<<<dim3(NQ_ / 32, D_ / 32, B_), blk, 0, stream>>>(query, Qth, Qtl);
  // DFT (rows 0..1151 via MFMA, mirror the rest)
  dft_mfma<<<dim3(9, 2, B_), blk, 0, stream>>>(Ch, Cl, Qth, Qtl, qrh, qrl);
  mirror2_kernel<<<dim3(960, B_), blk, 0, stream>>>(qrh, qrl);
  // projections
  proj_mfma<<<dim3(B_ * NQ_ / 128, 2), blk, 0, stream>>>(qrh, qrl, Wqh, Wql, bq, qh, ql);
  proj_mfma<<<dim3(B_ * NK_ / 128, 2), blk, 0, stream>>>(keyh, keyl, Wkh, Wkl, bk, kh, kl);
  vt_bf16_kernel<<<dim3(NK_ / 32, D_ / 32, B_), blk, 0, stream>>>(keyh, Vt);
  // attention
  scores_mfma<<<dim3(NQ_ / 128, NK_ / 128, B_), blk, 0, stream>>>(qh, ql, kh, kl, S);
  softmax_kernel<<<B_ * NQ_, blk, 0, stream>>>(S);
  pv_mfma<<<dim3(B_ * NQ_ / 128, D_ / 128), blk, 0, stream>>>(S, Vt, out);
}

// Round 4
// 384.237 us; speedup vs baseline: 2.8383x; 1.1607x over previous
//
#include <hip/hip_runtime.h>

#define B_ 8
#define NQ_ 2048
#define NK_ 2048
#define D_ 256

typedef __attribute__((ext_vector_type(8))) short bf16x8_t;
typedef __attribute__((ext_vector_type(4))) float f32x4_t;

static __device__ __forceinline__ unsigned short f2bf(float x) {
  unsigned int u = __float_as_uint(x);
  unsigned int r = (u + 0x7FFFu + ((u >> 16) & 1u)) >> 16;
  return (unsigned short)r;
}
static __device__ __forceinline__ float bf2f(unsigned short b) {
  return __uint_as_float(((unsigned int)b) << 16);
}

// ---------------------------------------------------------------------------
// generic f32 -> split bf16 (hi + lo)
// ---------------------------------------------------------------------------
__global__ __launch_bounds__(256) void split_kernel(const float* __restrict__ x,
                                                    unsigned short* __restrict__ xh,
                                                    unsigned short* __restrict__ xl,
                                                    int n) {
  const int i = blockIdx.x * 256 + threadIdx.x;
  if (i < n) {
    const float v = x[i];
    const unsigned short hb = f2bf(v);
    xh[i] = hb;
    xl[i] = f2bf(v - bf2f(hb));
  }
}

// C[i][n] = cos(2*pi*(i*n mod 2048)/2048), i in [0,1152), split bf16
__global__ __launch_bounds__(256) void cos_split_kernel(unsigned short* __restrict__ Ch,
                                                        unsigned short* __restrict__ Cl) {
  const int idx = blockIdx.x * 256 + threadIdx.x;
  const int i = idx >> 11, n = idx & 2047;
  const int m = (i * n) & 2047;
  const float c = cosf((float)m * 0.0030679615757712823f);
  const unsigned short hb = f2bf(c);
  Ch[idx] = hb;
  Cl[idx] = f2bf(c - bf2f(hb));
}

// Qt[b][d][n] = split(query[b][n][d])
__global__ __launch_bounds__(256) void qt_split_kernel(const float* __restrict__ q,
                                                       unsigned short* __restrict__ Qth,
                                                       unsigned short* __restrict__ Qtl) {
  __shared__ float lds[32][33];
  const int t  = threadIdx.x;
  const int n0 = blockIdx.x * 32;
  const int d0 = blockIdx.y * 32;
  const int b  = blockIdx.z;
#pragma unroll
  for (int p = 0; p < 4; ++p) {
    const int idx = t + 256 * p;
    const int dd = idx & 31, nn = idx >> 5;
    lds[nn][dd] = q[((size_t)b * NQ_ + n0 + nn) * D_ + d0 + dd];
  }
  __syncthreads();
#pragma unroll
  for (int p = 0; p < 4; ++p) {
    const int idx = t + 256 * p;
    const int nn = idx & 31, dd = idx >> 5;
    const float v = lds[nn][dd];
    const unsigned short hb = f2bf(v);
    const size_t o = ((size_t)b * D_ + d0 + dd) * NQ_ + n0 + nn;
    Qth[o] = hb;
    Qtl[o] = f2bf(v - bf2f(hb));
  }
}

// Vt[b][d][j] = keyh[b][j][d]
__global__ __launch_bounds__(256) void vt_bf16_kernel(const unsigned short* __restrict__ keyh,
                                                      unsigned short* __restrict__ Vt) {
  __shared__ unsigned short lds[32][40];
  const int t  = threadIdx.x;
  const int j0 = blockIdx.x * 32;
  const int d0 = blockIdx.y * 32;
  const int b  = blockIdx.z;
#pragma unroll
  for (int p = 0; p < 4; ++p) {
    const int idx = t + 256 * p;
    const int dd = idx & 31, jj = idx >> 5;
    lds[jj][dd] = keyh[((size_t)b * NK_ + j0 + jj) * D_ + d0 + dd];
  }
  __syncthreads();
#pragma unroll
  for (int p = 0; p < 4; ++p) {
    const int idx = t + 256 * p;
    const int jj = idx & 31, dd = idx >> 5;
    Vt[((size_t)b * D_ + d0 + dd) * NK_ + j0 + jj] = lds[jj][dd];
  }
}

// ---------------------------------------------------------------------------
// DFT via split-bf16 3-MFMA, K-split=4 (atomicAdd f32 partials into qr).
// Grid (9, 2, 32): z = b*4 + split. qr indexed [b][i<1152][d].
// ---------------------------------------------------------------------------
__global__ __launch_bounds__(256, 2) void dft_mfma(const unsigned short* __restrict__ Ch,
                                                   const unsigned short* __restrict__ Cl,
                                                   const unsigned short* __restrict__ Qth,
                                                   const unsigned short* __restrict__ Qtl,
                                                   float* __restrict__ qr) {
  __shared__ __align__(16) unsigned short Ah[128][72];
  __shared__ __align__(16) unsigned short Al[128][72];
  __shared__ __align__(16) unsigned short Bh[128][72];
  __shared__ __align__(16) unsigned short Bl[128][72];
  const int t = threadIdx.x;
  const int b = blockIdx.z >> 2, split = blockIdx.z & 3;
  const int i0 = blockIdx.x * 128, d0 = blockIdx.y * 128;
  const int w = t >> 6, lane = t & 63, quad = lane >> 4, l16 = lane & 15;
  const int wq = w & 1, wj = w >> 1;

  f32x4_t acc[4][4];
#pragma unroll
  for (int a = 0; a < 4; ++a)
#pragma unroll
    for (int c = 0; c < 4; ++c) acc[a][c] = (f32x4_t)0.f;

  const size_t abase = (size_t)i0 * 2048;
  const size_t bbase = ((size_t)b * D_ + d0) * 2048;

  for (int c0 = split * 512; c0 < split * 512 + 512; c0 += 64) {
#pragma unroll
    for (int it = 0; it < 4; ++it) {
      const int unit = t + 256 * it;
      const int row = unit >> 3, u = (unit & 7) * 8;
      const size_t go = (size_t)row * 2048 + c0 + u;
      *(uint4*)&Ah[row][u] = *(const uint4*)&Ch[abase + go];
      *(uint4*)&Al[row][u] = *(const uint4*)&Cl[abase + go];
      *(uint4*)&Bh[row][u] = *(const uint4*)&Qth[bbase + go];
      *(uint4*)&Bl[row][u] = *(const uint4*)&Qtl[bbase + go];
    }
    __syncthreads();
#pragma unroll
    for (int ks = 0; ks < 2; ++ks) {
      const int dcol = ks * 32 + quad * 8;
      bf16x8_t ah[4], al[4], bh[4], bl[4];
#pragma unroll
      for (int x = 0; x < 4; ++x) {
        ah[x] = *(const bf16x8_t*)&Ah[wq * 64 + x * 16 + l16][dcol];
        al[x] = *(const bf16x8_t*)&Al[wq * 64 + x * 16 + l16][dcol];
        bh[x] = *(const bf16x8_t*)&Bh[wj * 64 + x * 16 + l16][dcol];
        bl[x] = *(const bf16x8_t*)&Bl[wj * 64 + x * 16 + l16][dcol];
      }
#pragma unroll
      for (int at = 0; at < 4; ++at)
#pragma unroll
        for (int jt = 0; jt < 4; ++jt) {
          acc[at][jt] = __builtin_amdgcn_mfma_f32_16x16x32_bf16(ah[at], bh[jt], acc[at][jt], 0, 0, 0);
          acc[at][jt] = __builtin_amdgcn_mfma_f32_16x16x32_bf16(ah[at], bl[jt], acc[at][jt], 0, 0, 0);
          acc[at][jt] = __builtin_amdgcn_mfma_f32_16x16x32_bf16(al[at], bh[jt], acc[at][jt], 0, 0, 0);
        }
    }
    __syncthreads();
  }
#pragma unroll
  for (int at = 0; at < 4; ++at) {
#pragma unroll
    for (int jt = 0; jt < 4; ++jt) {
      const int d = d0 + wj * 64 + jt * 16 + l16;
#pragma unroll
      for (int r = 0; r < 4; ++r) {
        const int i = i0 + wq * 64 + at * 16 + quad * 4 + r;
        atomicAdd(&qr[((size_t)b * 1152 + i) * D_ + d], acc[at][jt][r]);
      }
    }
  }
}

// qrh/qrl[b][i][d] for all i in [0,2048): src = i<=1087 ? i : 2048-i
__global__ __launch_bounds__(256) void qr_finalize_kernel(const float* __restrict__ qr,
                                                          unsigned short* __restrict__ qrh,
                                                          unsigned short* __restrict__ qrl) {
  const int i = blockIdx.x, b = blockIdx.y, d = threadIdx.x;
  const int src = (i <= 1087) ? i : (2048 - i);
  const float v = qr[((size_t)b * 1152 + src) * D_ + d];
  const unsigned short hb = f2bf(v);
  const size_t o = ((size_t)b * NQ_ + i) * D_ + d;
  qrh[o] = hb;
  qrl[o] = f2bf(v - bf2f(hb));
}

// ---------------------------------------------------------------------------
// y = x @ W.T + bias -- split-bf16 3-MFMA, split epilogue (verified r3)
// ---------------------------------------------------------------------------
__global__ __launch_bounds__(256, 2) void proj_mfma(const unsigned short* __restrict__ xh,
                                                    const unsigned short* __restrict__ xl,
                                                    const unsigned short* __restrict__ Wh,
                                                    const unsigned short* __restrict__ Wl,
                                                    const float* __restrict__ bias,
                                                    unsigned short* __restrict__ yh,
                                                    unsigned short* __restrict__ yl) {
  __shared__ __align__(16) unsigned short Xh[128][72];
  __shared__ __align__(16) unsigned short Xl[128][72];
  __shared__ __align__(16) unsigned short Bh[128][72];
  __shared__ __align__(16) unsigned short Bl[128][72];
  const int t = threadIdx.x;
  const int m0 = blockIdx.x * 128, o0 = blockIdx.y * 128;
  const int w = t >> 6, lane = t & 63, quad = lane >> 4, l16 = lane & 15;
  const int wq = w & 1, wj = w >> 1;

  f32x4_t acc[4][4];
#pragma unroll
  for (int a = 0; a < 4; ++a)
#pragma unroll
    for (int c = 0; c < 4; ++c) acc[a][c] = (f32x4_t)0.f;

  const size_t xbase = (size_t)m0 * D_;
  const size_t wbase = (size_t)o0 * D_;

  for (int c0 = 0; c0 < D_; c0 += 64) {
#pragma unroll
    for (int it = 0; it < 4; ++it) {
      const int unit = t + 256 * it;
      const int row = unit >> 3, u = (unit & 7) * 8;
      const size_t go = (size_t)row * D_ + c0 + u;
      *(uint4*)&Xh[row][u] = *(const uint4*)&xh[xbase + go];
      *(uint4*)&Xl[row][u] = *(const uint4*)&xl[xbase + go];
      *(uint4*)&Bh[row][u] = *(const uint4*)&Wh[wbase + go];
      *(uint4*)&Bl[row][u] = *(const uint4*)&Wl[wbase + go];
    }
    __syncthreads();
#pragma unroll
    for (int ks = 0; ks < 2; ++ks) {
      const int dcol = ks * 32 + quad * 8;
      bf16x8_t ah[4], al[4], bh[4], bl[4];
#pragma unroll
      for (int x = 0; x < 4; ++x) {
        ah[x] = *(const bf16x8_t*)&Xh[wq * 64 + x * 16 + l16][dcol];
        al[x] = *(const bf16x8_t*)&Xl[wq * 64 + x * 16 + l16][dcol];
        bh[x] = *(const bf16x8_t*)&Bh[wj * 64 + x * 16 + l16][dcol];
        bl[x] = *(const bf16x8_t*)&Bl[wj * 64 + x * 16 + l16][dcol];
      }
#pragma unroll
      for (int at = 0; at < 4; ++at)
#pragma unroll
        for (int jt = 0; jt < 4; ++jt) {
          acc[at][jt] = __builtin_amdgcn_mfma_f32_16x16x32_bf16(ah[at], bh[jt], acc[at][jt], 0, 0, 0);
          acc[at][jt] = __builtin_amdgcn_mfma_f32_16x16x32_bf16(ah[at], bl[jt], acc[at][jt], 0, 0, 0);
          acc[at][jt] = __builtin_amdgcn_mfma_f32_16x16x32_bf16(al[at], bh[jt], acc[at][jt], 0, 0, 0);
        }
    }
    __syncthreads();
  }
#pragma unroll
  for (int at = 0; at < 4; ++at) {
#pragma unroll
    for (int jt = 0; jt < 4; ++jt) {
      const int o = o0 + wj * 64 + jt * 16 + l16;
      const float bv = bias[o];
#pragma unroll
      for (int r = 0; r < 4; ++r) {
        const int m = m0 + wq * 64 + at * 16 + quad * 4 + r;
        const float v = acc[at][jt][r] + bv;
        const unsigned short hb = f2bf(v);
        yh[(size_t)m * D_ + o] = hb;
        yl[(size_t)m * D_ + o] = f2bf(v - bf2f(hb));
      }
    }
  }
}

// ---------------------------------------------------------------------------
// S = scale * q.k -- split-bf16 3-MFMA (verified r2/r3)
// ---------------------------------------------------------------------------
__global__ __launch_bounds__(256, 2) void scores_mfma(const unsigned short* __restrict__ qh,
                                                      const unsigned short* __restrict__ ql,
                                                      const unsigned short* __restrict__ kh,
                                                      const unsigned short* __restrict__ kl,
                                                      float* __restrict__ S) {
  __shared__ __align__(16) unsigned short Qh[128][72];
  __shared__ __align__(16) unsigned short Ql[128][72];
  __shared__ __align__(16) unsigned short Kh[128][72];
  __shared__ __align__(16) unsigned short Kl[128][72];
  const int t = threadIdx.x;
  const int b = blockIdx.z;
  const int i0 = blockIdx.x * 128, j0 = blockIdx.y * 128;
  const int w = t >> 6, lane = t & 63, quad = lane >> 4, l16 = lane & 15;
  const int wq = w & 1, wj = w >> 1;

  f32x4_t acc[4][4];
#pragma unroll
  for (int a = 0; a < 4; ++a)
#pragma unroll
    for (int c = 0; c < 4; ++c) acc[a][c] = (f32x4_t)0.f;

  const size_t qbase = ((size_t)b * NQ_ + i0) * D_;
  const size_t kbase = ((size_t)b * NK_ + j0) * D_;

  for (int c0 = 0; c0 < D_; c0 += 64) {
#pragma unroll
    for (int it = 0; it < 4; ++it) {
      const int unit = t + 256 * it;
      const int row = unit >> 3, u = (unit & 7) * 8;
      const size_t go = (size_t)row * D_ + c0 + u;
      *(uint4*)&Qh[row][u] = *(const uint4*)&qh[qbase + go];
      *(uint4*)&Ql[row][u] = *(const uint4*)&ql[qbase + go];
      *(uint4*)&Kh[row][u] = *(const uint4*)&kh[kbase + go];
      *(uint4*)&Kl[row][u] = *(const uint4*)&kl[kbase + go];
    }
    __syncthreads();
#pragma unroll
    for (int ks = 0; ks < 2; ++ks) {
      const int dcol = ks * 32 + quad * 8;
      bf16x8_t ah[4], al[4], bh[4], bl[4];
#pragma unroll
      for (int x = 0; x < 4; ++x) {
        ah[x] = *(const bf16x8_t*)&Qh[wq * 64 + x * 16 + l16][dcol];
        al[x] = *(const bf16x8_t*)&Ql[wq * 64 + x * 16 + l16][dcol];
        bh[x] = *(const bf16x8_t*)&Kh[wj * 64 + x * 16 + l16][dcol];
        bl[x] = *(const bf16x8_t*)&Kl[wj * 64 + x * 16 + l16][dcol];
      }
#pragma unroll
      for (int at = 0; at < 4; ++at)
#pragma unroll
        for (int jt = 0; jt < 4; ++jt) {
          acc[at][jt] = __builtin_amdgcn_mfma_f32_16x16x32_bf16(ah[at], bh[jt], acc[at][jt], 0, 0, 0);
          acc[at][jt] = __builtin_amdgcn_mfma_f32_16x16x32_bf16(ah[at], bl[jt], acc[at][jt], 0, 0, 0);
          acc[at][jt] = __builtin_amdgcn_mfma_f32_16x16x32_bf16(al[at], bh[jt], acc[at][jt], 0, 0, 0);
        }
    }
    __syncthreads();
  }
  const float scale = 0.0625f;
#pragma unroll
  for (int at = 0; at < 4; ++at) {
#pragma unroll
    for (int jt = 0; jt < 4; ++jt) {
      const int j = j0 + wj * 64 + jt * 16 + l16;
#pragma unroll
      for (int r = 0; r < 4; ++r) {
        const int i = i0 + wq * 64 + at * 16 + quad * 4 + r;
        S[((size_t)b * NQ_ + i) * NK_ + j] = acc[at][jt][r] * scale;
      }
    }
  }
}

// ---------------------------------------------------------------------------
// per-row max and 1/sum(exp): one wave per row
// ---------------------------------------------------------------------------
__global__ __launch_bounds__(256) void rowstat_kernel(const float* __restrict__ S,
                                                      float2* __restrict__ stat) {
  const int row = blockIdx.x * 4 + (threadIdx.x >> 6);
  const int lane = threadIdx.x & 63;
  const float4* Sr = (const float4*)(S + (size_t)row * NK_);
  float4 v[8];
#pragma unroll
  for (int p = 0; p < 8; ++p) v[p] = Sr[lane + 64 * p];

  float m = v[0].x;
#pragma unroll
  for (int p = 0; p < 8; ++p)
    m = fmaxf(m, fmaxf(fmaxf(v[p].x, v[p].y), fmaxf(v[p].z, v[p].w)));
#pragma unroll
  for (int off = 1; off < 64; off <<= 1) m = fmaxf(m, __shfl_xor(m, off));

  float s = 0.f;
#pragma unroll
  for (int p = 0; p < 8; ++p)
    s += __expf(v[p].x - m) + __expf(v[p].y - m) + __expf(v[p].z - m) + __expf(v[p].w - m);
#pragma unroll
  for (int off = 1; off < 64; off <<= 1) s += __shfl_xor(s, off);

  if (lane == 0) stat[row] = make_float2(m, 1.0f / s);
}

// ---------------------------------------------------------------------------
// out[m,d] += sum_{j in split} exp(S[m,j]-mrow)*invl * V[j,d]
// Block: 128 rows x full 256 d, 4 waves (64 rows x 128 d each). j-split=4.
// ---------------------------------------------------------------------------
__global__ __launch_bounds__(256, 2) void pv_mfma(const float* __restrict__ S,
                                                  const float2* __restrict__ stat,
                                                  const unsigned short* __restrict__ Vt,
                                                  float* __restrict__ out) {
  __shared__ __align__(16) unsigned short Ps[128][72];
  __shared__ __align__(16) unsigned short Vs[256][72];
  const int t = threadIdx.x;
  const int m0 = blockIdx.x * 128;
  const int b  = blockIdx.x >> 4;
  const int j0 = blockIdx.y * 512;
  const int w = t >> 6, lane = t & 63, quad = lane >> 4, l16 = lane & 15;
  const int wq = w & 1, wd = w >> 1;   // row half / d half (128 each)

  f32x4_t acc[4][8];
#pragma unroll
  for (int a = 0; a < 4; ++a)
#pragma unroll
    for (int c = 0; c < 8; ++c) acc[a][c] = (f32x4_t)0.f;

  for (int jc = 0; jc < 512; jc += 64) {
    // stage P tile with fused exp-normalize (f32 -> bf16)
#pragma unroll
    for (int it = 0; it < 8; ++it) {
      const int unit = t + 256 * it;
      const int row = unit >> 4, u = (unit & 15) * 4;
      const float2 st = stat[m0 + row];
      const float4 v = *(const float4*)&S[((size_t)(m0 + row)) * NK_ + j0 + jc + u];
      const float px = __expf(v.x - st.x) * st.y;
      const float py = __expf(v.y - st.x) * st.y;
      const float pz = __expf(v.z - st.x) * st.y;
      const float pw = __expf(v.w - st.x) * st.y;
      uint2 pk;
      pk.x = (unsigned int)f2bf(px) | ((unsigned int)f2bf(py) << 16);
      pk.y = (unsigned int)f2bf(pz) | ((unsigned int)f2bf(pw) << 16);
      *(uint2*)&Ps[row][u] = pk;
    }
    // stage Vt tile: 256 d-rows x 64 j
#pragma unroll
    for (int it = 0; it < 8; ++it) {
      const int unit = t + 256 * it;
      const int row = unit >> 3, u = (unit & 7) * 8;
      *(uint4*)&Vs[row][u] = *(const uint4*)&Vt[((size_t)b * D_ + row) * NK_ + j0 + jc + u];
    }
    __syncthreads();
#pragma unroll
    for (int ks = 0; ks < 2; ++ks) {
      const int jcol = ks * 32 + quad * 8;
      bf16x8_t a[4], bv[8];
#pragma unroll
      for (int x = 0; x < 4; ++x)
        a[x] = *(const bf16x8_t*)&Ps[wq * 64 + x * 16 + l16][jcol];
#pragma unroll
      for (int y = 0; y < 8; ++y)
        bv[y] = *(const bf16x8_t*)&Vs[wd * 128 + y * 16 + l16][jcol];
#pragma unroll
      for (int at = 0; at < 4; ++at)
#pragma unroll
        for (int bt = 0; bt < 8; ++bt)
          acc[at][bt] = __builtin_amdgcn_mfma_f32_16x16x32_bf16(a[at], bv[bt], acc[at][bt], 0, 0, 0);
    }
    __syncthreads();
  }
#pragma unroll
  for (int at = 0; at < 4; ++at) {
#pragma unroll
    for (int bt = 0; bt < 8; ++bt) {
      const int d = wd * 128 + bt * 16 + l16;
#pragma unroll
      for (int r = 0; r < 4; ++r) {
        const int m = m0 + wq * 64 + at * 16 + quad * 4 + r;
        atomicAdd(&out[(size_t)m * D_ + d], acc[at][bt][r]);
      }
    }
  }
}

extern "C" void kernel_launch(void* const* d_in, const int* in_sizes, int n_in,
                              void* d_out, int out_size, void* d_ws, size_t ws_size,
                              hipStream_t stream) {
  const float* query = (const float*)d_in[0];
  const float* key   = (const float*)d_in[1];
  const float* Wq    = (const float*)d_in[2];
  const float* bq    = (const float*)d_in[3];
  const float* Wk    = (const float*)d_in[4];
  const float* bk    = (const float*)d_in[5];
  float* out = (float*)d_out;

  char* ws = (char*)d_ws;
  const size_t MB = (size_t)1 << 20;
  // persistent:
  unsigned short* qh = (unsigned short*)(ws);            // 8 MB (reused as stat after scores)
  unsigned short* ql = (unsigned short*)(ws + 8 * MB);
  unsigned short* kh = (unsigned short*)(ws + 16 * MB);
  unsigned short* kl = (unsigned short*)(ws + 24 * MB);
  unsigned short* Vt = (unsigned short*)(ws + 32 * MB);
  float* S = (float*)(ws + 40 * MB);                     // 128 MB
  float2* stat = (float2*)(ws + 168 * MB);               // 128 KB (ws >= 176 MB, verified r1)
  // transient (inside S region, dead before scores writes S):
  unsigned short* Ch   = (unsigned short*)(ws + 40 * MB);   // 4.5 MB
  unsigned short* Cl   = (unsigned short*)(ws + 45 * MB);   // 4.5 MB
  unsigned short* Qth  = (unsigned short*)(ws + 50 * MB);   // 8 MB
  unsigned short* Qtl  = (unsigned short*)(ws + 58 * MB);   // 8 MB
  float*          qr   = (float*)(ws + 66 * MB);            // 9.44 MB f32 [8][1152][256]
  unsigned short* qrh  = (unsigned short*)(ws + 78 * MB);   // 8 MB
  unsigned short* qrl  = (unsigned short*)(ws + 86 * MB);   // 8 MB
  unsigned short* keyh = (unsigned short*)(ws + 94 * MB);   // 8 MB
  unsigned short* keyl = (unsigned short*)(ws + 102 * MB);  // 8 MB
  unsigned short* Wqh  = (unsigned short*)(ws + 110 * MB);  // 128 KB
  unsigned short* Wql  = (unsigned short*)(ws + 110 * MB + 256 * 1024);
  unsigned short* Wkh  = (unsigned short*)(ws + 110 * MB + 512 * 1024);
  unsigned short* Wkl  = (unsigned short*)(ws + 110 * MB + 768 * 1024);

  dim3 blk(256);
  hipMemsetAsync(qr, 0, (size_t)B_ * 1152 * D_ * sizeof(float), stream);
  hipMemsetAsync(out, 0, (size_t)B_ * NQ_ * D_ * sizeof(float), stream);

  split_kernel<<<B_ * NK_ * D_ / 256, blk, 0, stream>>>(key, keyh, keyl, B_ * NK_ * D_);
  split_kernel<<<D_ * D_ / 256, blk, 0, stream>>>(Wq, Wqh, Wql, D_ * D_);
  split_kernel<<<D_ * D_ / 256, blk, 0, stream>>>(Wk, Wkh, Wkl, D_ * D_);
  cos_split_kernel<<<1152 * 2048 / 256, blk, 0, stream>>>(Ch, Cl);
  qt_split_kernel<<<dim3(NQ_ / 32, D_ / 32, B_), blk, 0, stream>>>(query, Qth, Qtl);
  // DFT: K-split=4, atomic f32 partials, then finalize (split + mirror)
  dft_mfma<<<dim3(9, 2, B_ * 4), blk, 0, stream>>>(Ch, Cl, Qth, Qtl, qr);
  qr_finalize_kernel<<<dim3(2048, B_), blk, 0, stream>>>(qr, qrh, qrl);
  // projections
  proj_mfma<<<dim3(B_ * NQ_ / 128, 2), blk, 0, stream>>>(qrh, qrl, Wqh, Wql, bq, qh, ql);
  proj_mfma<<<dim3(B_ * NK_ / 128, 2), blk, 0, stream>>>(keyh, keyl, Wkh, Wkl, bk, kh, kl);
  vt_bf16_kernel<<<dim3(NK_ / 32, D_ / 32, B_), blk, 0, stream>>>(keyh, Vt);
  // attention
  scores_mfma<<<dim3(NQ_ / 128, NK_ / 128, B_), blk, 0, stream>>>(qh, ql, kh, kl, S);
  rowstat_kernel<<<B_ * NQ_ / 4, blk, 0, stream>>>(S, stat);
  pv_mfma<<<dim3(B_ * NQ_ / 128, 4), blk, 0, stream>>>(S, stat, Vt, out);
}